// Round 8
// baseline (9499.841 us; speedup 1.0000x reference)
//
#include <hip/hip_runtime.h>
#include <math.h>

#define B_DIM   8192
#define N_DIM   784
#define NPAD    800          // 25*32, K/N pad for NN GEMM / Rbf
#define NROWS_W 896          // 7*128, row-pad for Wbf (NT B operand, 128-wide n-tiles)
#define M_DIM   2048
#define XSZ     (B_DIM*N_DIM)
#define GSZ     (B_DIM*M_DIM)
#define NITER   50
#define PITER   100

typedef __attribute__((ext_vector_type(8))) short short8;
typedef __attribute__((ext_vector_type(4))) float floatx4;

// ---------------- async global->LDS (16B per lane, wave-uniform LDS base) ----------------
__device__ __forceinline__ void async_ld16(const unsigned short* g, unsigned short* l){
  __builtin_amdgcn_global_load_lds(
      (const __attribute__((address_space(1))) unsigned int*)g,
      (__attribute__((address_space(3))) unsigned int*)l,
      16, 0, 0);
}

// ---------------- threefry + erfinv (reproduce jax.random.normal(key(1),(1,2048))) ------------
__device__ __forceinline__ unsigned rotl32(unsigned x, int d){ return (x<<d)|(x>>(32-d)); }

__device__ void threefry2x32(unsigned& v0, unsigned& v1){
  const unsigned ks0=0u, ks1=1u, ks2=0x1BD11BDBu;
  unsigned x0=v0+ks0, x1=v1+ks1;
#define RND(R) { x0+=x1; x1=rotl32(x1,R); x1^=x0; }
  RND(13) RND(15) RND(26) RND(6)
  x0+=ks1; x1+=ks2+1u;
  RND(17) RND(29) RND(16) RND(24)
  x0+=ks2; x1+=ks0+2u;
  RND(13) RND(15) RND(26) RND(6)
  x0+=ks0; x1+=ks1+3u;
  RND(17) RND(29) RND(16) RND(24)
  x0+=ks1; x1+=ks2+4u;
  RND(13) RND(15) RND(26) RND(6)
  x0+=ks2; x1+=ks0+5u;
#undef RND
  v0=x0; v1=x1;
}

__device__ float erfinv_f(float x){
  float w = -logf((1.0f-x)*(1.0f+x));
  float p;
  if (w < 5.0f){
    w -= 2.5f;
    p = 2.81022636e-08f;
    p = fmaf(p,w, 3.43273939e-07f);
    p = fmaf(p,w,-3.5233877e-06f);
    p = fmaf(p,w,-4.39150654e-06f);
    p = fmaf(p,w, 0.00021858087f);
    p = fmaf(p,w,-0.00125372503f);
    p = fmaf(p,w,-0.00417768164f);
    p = fmaf(p,w, 0.246640727f);
    p = fmaf(p,w, 1.50140941f);
  } else {
    w = sqrtf(w) - 3.0f;
    p = -0.000200214257f;
    p = fmaf(p,w, 0.000100950558f);
    p = fmaf(p,w, 0.00134934322f);
    p = fmaf(p,w,-0.00367342844f);
    p = fmaf(p,w, 0.00573950773f);
    p = fmaf(p,w,-0.0076224613f);
    p = fmaf(p,w, 0.00943887047f);
    p = fmaf(p,w, 1.00167406f);
    p = fmaf(p,w, 2.83297682f);
  }
  return p*x;
}

__device__ float bits_to_normal(unsigned b){
  unsigned fb = (b>>9) | 0x3f800000u;
  float u01 = __uint_as_float(fb) - 1.0f;
  const float lo = -0.99999994f;
  float u = u01*(1.0f - lo) + lo;
  u = fmaxf(lo, u);
  return 1.41421356237f * erfinv_f(u);
}

__global__ void setup_kernel(float* __restrict__ xbuf0, float* __restrict__ accs){
  int i = threadIdx.x;   // 1024 threads
  if (i < 64) accs[i] = 0.0f;
  unsigned v0 = (unsigned)i, v1 = (unsigned)(1024+i);
  threefry2x32(v0, v1);
  xbuf0[i]        = bits_to_normal(v0);
  xbuf0[1024 + i] = bits_to_normal(v1);
}

// ---------------- bf16 convert helpers ----------------
__device__ __forceinline__ unsigned short f2bf(float f){
  unsigned u = __float_as_uint(f);
  unsigned r = (u + 0x7fffu + ((u>>16)&1u)) >> 16;
  return (unsigned short)r;
}
__device__ __forceinline__ unsigned pack2(float a, float b){
  return (unsigned)f2bf(a) | ((unsigned)f2bf(b) << 16);
}
__device__ __forceinline__ float bf2f(unsigned short s){
  return __uint_as_float(((unsigned)s) << 16);
}

// Wbf[j][k] = bf16(W[j][k]) : 896 x 2048, rows >=784 zeroed
__global__ void conv_w(const float* __restrict__ W, unsigned short* __restrict__ Wbf){
  int i4 = (blockIdx.x*256 + threadIdx.x)*4;   // over 896*2048 -> 1792 blocks
  int row = i4 >> 11;
  uint2 p = make_uint2(0,0);
  if (row < N_DIM){
    float4 v = *(const float4*)(W + (size_t)row*M_DIM + (i4 & 2047));
    p.x = pack2(v.x, v.y); p.y = pack2(v.z, v.w);
  }
  *(uint2*)(Wbf + i4) = p;
}

// Ybf[i][j] = bf16(Y[i][j]) : 8192 x 800, cols >=784 zeroed  (stored into Rbf buffer)
__global__ void conv_y(const float* __restrict__ Y, unsigned short* __restrict__ Ybf){
  int row = blockIdx.x;
  int c4 = threadIdx.x*4;
  if (c4 >= NPAD) return;
  uint2 p = make_uint2(0,0);
  if (c4 < N_DIM){
    float4 v = *(const float4*)(Y + (size_t)row*N_DIM + c4);
    p.x = pack2(v.x, v.y); p.y = pack2(v.z, v.w);
  }
  *(uint2*)(Ybf + (size_t)row*NPAD + c4) = p;
}

// WTbf[k][j] = bf16(W[j][k]) : 2048 x 800 (j in [784,800) -> 0)
__global__ void transpose_w(const float* __restrict__ W, unsigned short* __restrict__ WTbf){
  __shared__ float tile[32][33];
  int k0 = blockIdx.x*32;
  int j0 = blockIdx.y*32;
  int tx = threadIdx.x & 31, ty = threadIdx.x >> 5;
#pragma unroll
  for (int i=0;i<4;i++){
    int j = j0 + ty + 8*i;
    float v = (j < N_DIM) ? W[(size_t)j*M_DIM + k0 + tx] : 0.0f;
    tile[tx][ty+8*i] = v;
  }
  __syncthreads();
#pragma unroll
  for (int i=0;i<4;i++){
    int k = k0 + ty + 8*i;
    WTbf[(size_t)k*NPAD + j0 + tx] = f2bf(tile[ty+8*i][tx]);
  }
}

// ---------------- Q = W^T W (fp32 VALU GEMM, one-time, power-method only) ----------------
__global__ __launch_bounds__(256)
void compute_q(const float* __restrict__ W, float* __restrict__ Q){
  __shared__ float As2[16][132];
  __shared__ float Bs2[16][132];
  const int t = threadIdx.x;
  const int a0 = blockIdx.x*128, b0 = blockIdx.y*128;
  const int ty = t>>4, tx = t&15;
  float acc[8][8];
#pragma unroll
  for (int i=0;i<8;i++)
#pragma unroll
    for (int j=0;j<8;j++) acc[i][j]=0.0f;

  for (int j0=0; j0<N_DIM; j0+=16){
#pragma unroll
    for (int h=0; h<8; ++h){
      int idx = h*256 + t;
      int r = idx>>7, c = idx&127;
      As2[r][c] = W[(size_t)(j0+r)*M_DIM + a0 + c];
      Bs2[r][c] = W[(size_t)(j0+r)*M_DIM + b0 + c];
    }
    __syncthreads();
#pragma unroll
    for (int kk=0; kk<16; ++kk){
      float a[8], b[8];
#pragma unroll
      for (int i=0;i<8;i++) a[i] = As2[kk][ty*8+i];
#pragma unroll
      for (int j=0;j<8;j++) b[j] = Bs2[kk][tx*8+j];
#pragma unroll
      for (int i=0;i<8;i++)
#pragma unroll
        for (int j=0;j<8;j++) acc[i][j] = fmaf(a[i], b[j], acc[i][j]);
    }
    __syncthreads();
  }
#pragma unroll
  for (int i=0;i<8;i++){
    int a = a0 + ty*8 + i;
#pragma unroll
    for (int j=0;j<8;j++) Q[(size_t)a*M_DIM + b0 + tx*8 + j] = acc[i][j];
  }
}

// ---------------- reductions ----------------
__global__ void sumsq_kernel(const float* __restrict__ v, int n, float* __restrict__ acc){
  __shared__ float red[256];
  int t = threadIdx.x;
  float s = 0.0f;
  for (int i = blockIdx.x*256 + t; i < n; i += gridDim.x*256){ float x = v[i]; s = fmaf(x,x,s); }
  red[t] = s; __syncthreads();
  for (int off=128; off>0; off>>=1){ if (t<off) red[t]+=red[t+off]; __syncthreads(); }
  if (t==0) atomicAdd(acc, red[0]);
}

// ---------------- power method on Q (symmetric) ----------------
__global__ void pm_q(const float* __restrict__ x, const float* __restrict__ Q,
                     float* __restrict__ xout){
  __shared__ float red[256];
  int t = threadIdx.x;
  float s = 0.0f;
  for (int k=t; k<M_DIM; k+=256){ float v = x[k]; s = fmaf(v,v,s); }
  red[t]=s; __syncthreads();
  for (int off=128; off>0; off>>=1){ if (t<off) red[t]+=red[t+off]; __syncthreads(); }
  float inv = 1.0f/sqrtf(red[0]);
  int wave = t>>6, lane = t&63;
  int j = blockIdx.x*4 + wave;
  const float* Qr = Q + (size_t)j*M_DIM;
  float acc = 0.0f;
  for (int k=lane; k<M_DIM; k+=64) acc = fmaf(x[k], Qr[k], acc);
  for (int off=32; off>0; off>>=1) acc += __shfl_down(acc, off);
  if (lane==0) xout[j] = acc * inv;
}

// params: [0]=c, [1]=eta=1/c, [2]=lam/c, [3]=||Y||
__global__ void finish_power(const float* __restrict__ xfin, const float* __restrict__ accs,
                             float* __restrict__ params){
  __shared__ float red[256];
  int t = threadIdx.x;
  float s = 0.0f;
  for (int k=t; k<M_DIM; k+=256){ float v = xfin[k]; s = fmaf(v,v,s); }
  red[t]=s; __syncthreads();
  for (int off=128; off>0; off>>=1){ if (t<off) red[t]+=red[t+off]; __syncthreads(); }
  if (t==0){
    float c = sqrtf(red[0]);
    params[0] = c;
    params[1] = 1.0f/c;
    params[2] = 0.1f/c;
    params[3] = sqrtf(accs[0]);
  }
}

__device__ __forceinline__ float softthr(float v, float th){
  float a = fmaxf(fabsf(v) - th, 0.0f);
  return copysignf(a, v);
}

// ================= MFMA GEMM NT: C[i,j] = sum_k A[i,k]*B[j,k] =================
// Tile 64x128. Grid 896 (1D, XCD-swizzled: XCD g8 owns a 16m x 7n panel).
// A = Zhi bf16 [8192 x 2048], B = Wbf bf16 [896 x 2048] (rows>=784 zero), both async.
// MODE 0: R = A*B^T - Y -> Rbf (bf16, stride NPAD, cols [784,800) zeroed), ||R||^2 -> nacc.
// MODE 1: X = A*B^T (fp32 out; A holds bf16 of final Gamma).
template<int MODE>
__global__ __launch_bounds__(256)
void mfma_nt(const unsigned short* __restrict__ Abf,
             const unsigned short* __restrict__ Bbf,
             const float* __restrict__ Y,
             unsigned short* __restrict__ Rbf,
             float* __restrict__ X,
             float* __restrict__ nacc){
  __shared__ float4 smem4[1024];                 // 16 KB
  unsigned short* As = (unsigned short*)smem4;   // [64 x 32]  4 KB
  unsigned short* Bs = As + 64*32;               // [128 x 32] 8 KB
  float* fbuf = (float*)smem4;                   // [64 x 64] fp32 epilogue chunk (16 KB)

  const int bid = blockIdx.x;
  const int g8  = bid & 7, w = bid >> 3;         // w in [0,112): 16m x 7n panel
  const int mt  = w / 7, nt = w - mt*7;
  const int m0  = (g8*16 + mt)*64;
  const int n0  = nt*128;

  const int t    = threadIdx.x;
  const int wave = t>>6, lane = t&63;
  const int wm2  = wave>>1, wn2 = wave&1;        // 2x2 waves over 64x128
  const int quad = lane>>4, l15 = lane&15;
  const int lrow = lane>>2;
  const int lk   = (lane&3)*8;

  floatx4 acc[2][4];
#pragma unroll
  for (int i=0;i<2;i++)
#pragma unroll
    for (int j=0;j<4;j++) acc[i][j] = (floatx4)(0.0f);

  for (int k0=0; k0<M_DIM; k0+=32){
    // A: 64x32 = 4 chunks of 16 rows; one async per thread
    async_ld16(Abf + (size_t)(m0 + wave*16 + lrow)*M_DIM + k0 + lk, &As[wave*512]);
    // B: 128x32 = 8 chunks; 2 per wave
#pragma unroll
    for (int c=0; c<2; ++c){
      int chunk = wave*2 + c;
      async_ld16(Bbf + (size_t)(n0 + chunk*16 + lrow)*M_DIM + k0 + lk, &Bs[chunk*512]);
    }
    __syncthreads();
    short8 af[2], bfr[4];
#pragma unroll
    for (int ti=0; ti<2; ++ti)
      af[ti] = *(const short8*)&As[(wm2*32 + ti*16 + l15)*32 + quad*8];
#pragma unroll
    for (int tj=0; tj<4; ++tj)
      bfr[tj] = *(const short8*)&Bs[(wn2*64 + tj*16 + l15)*32 + quad*8];
#pragma unroll
    for (int ti=0; ti<2; ++ti)
#pragma unroll
      for (int tj=0; tj<4; ++tj)
        acc[ti][tj] = __builtin_amdgcn_mfma_f32_16x16x32_bf16(af[ti], bfr[tj], acc[ti][tj], 0, 0, 0);
    __syncthreads();
  }

  // ---- coalesced epilogue: 2 chunks of [64 rows x 64 cols] via LDS ----
  float ss = 0.0f;
#pragma unroll
  for (int c=0; c<2; ++c){
    if (wn2 == c){
#pragma unroll
      for (int ti=0; ti<2; ++ti)
#pragma unroll
        for (int tj=0; tj<4; ++tj)
#pragma unroll
          for (int r=0; r<4; ++r)
            fbuf[(wm2*32 + ti*16 + quad*4 + r)*64 + tj*16 + l15] = acc[ti][tj][r];
    }
    __syncthreads();
#pragma unroll
    for (int k=0; k<4; ++k){
      int row = k*16 + (t>>4);
      int col = (t&15)*4;
      int m = m0 + row;
      int n = n0 + c*64 + col;
      float4 v = *(const float4*)&fbuf[row*64 + col];
      if (MODE==0){
        if (n < N_DIM){
          float4 yv = *(const float4*)(Y + (size_t)m*N_DIM + n);
          float r0 = v.x - yv.x, r1 = v.y - yv.y, r2 = v.z - yv.z, r3 = v.w - yv.w;
          uint2 p; p.x = pack2(r0, r1); p.y = pack2(r2, r3);
          *(uint2*)(Rbf + (size_t)m*NPAD + n) = p;
          ss = fmaf(r0,r0, fmaf(r1,r1, fmaf(r2,r2, fmaf(r3,r3, ss))));
        } else if (n < NPAD){
          *(uint2*)(Rbf + (size_t)m*NPAD + n) = make_uint2(0,0);
        }
      } else {
        if (n < N_DIM) *(float4*)(X + (size_t)m*N_DIM + n) = v;
      }
    }
    __syncthreads();
  }

  if (MODE==0){
    for (int off=32; off>0; off>>=1) ss += __shfl_down(ss, off);
    if (lane==0) atomicAdd(nacc, ss);
  }
}

// ================= MFMA GEMM NN: G[i,n] = sum_j A[i,j]*WT[n,j] ==========
// Tile 128x128. Grid 1024 (1D, XCD-swizzled: XCD g8 owns an 8m x 16n panel -> its
// 1024-row A-slab (1.6 MB) + all of WTbf (3.3 MB) are XCD-L2-resident). 4 blocks/CU.
// A = Rbf/Ybf [8192 x 800] (async), B = WTbf [2048 x 800] (async).
// State: z as hi/lo bf16 pair; Gamma fp32 (graded output).
// MODE 0 (init, A=Ybf): g=soft(eta*G,0.1); Gamma=g; z=g -> hi/lo.
// MODE 1 (iter, A=Rbf): z=hi+lo; g=soft(z-eta*G,lam/c); zn=g+mu*(g-go); store hi/lo.
// MODE 2 (last iter):   g=soft(z-eta*G,lam/c); Gamma=g; Zhi=bf16(g) [A for final X GEMM].
template<int MODE>
__global__ __launch_bounds__(256)
void mfma_nn(const unsigned short* __restrict__ Abf,
             const unsigned short* __restrict__ WTbf,
             float* __restrict__ Gamma,
             unsigned short* __restrict__ Zhi,
             unsigned short* __restrict__ Zlo,
             const float* __restrict__ params,
             float mu){
  __shared__ float4 smem4[1024];                 // 16 KB
  unsigned short* As = (unsigned short*)smem4;   // [128 x 32] 8 KB
  unsigned short* Bs = As + 128*32;              // [128 x 32] 8 KB
  float* fbuf = (float*)smem4;                   // [128 x 32] fp32 epilogue chunk (16 KB)

  const int bid = blockIdx.x;
  const int g8  = bid & 7, w = bid >> 3;         // w in [0,128): 8m x 16n panel
  const int m0  = (g8*8 + (w>>4))*128;
  const int n0  = (w & 15)*128;

  const int t    = threadIdx.x;
  const int wave = t>>6, lane = t&63;
  const int wm   = wave>>1, wn = wave&1;
  const int quad = lane>>4, l15 = lane&15;
  const int ch0  = wave*2;
  const int lrow = lane>>2;
  const int lk   = (lane&3)*8;

  floatx4 acc[4][4];
#pragma unroll
  for (int i=0;i<4;i++)
#pragma unroll
    for (int j=0;j<4;j++) acc[i][j] = (floatx4)(0.0f);

  for (int k0=0; k0<NPAD; k0+=32){
#pragma unroll
    for (int c=0; c<2; ++c){
      int chunk = ch0 + c;
      async_ld16(Abf  + (size_t)(m0 + chunk*16 + lrow)*NPAD + k0 + lk, &As[chunk*512]);
      async_ld16(WTbf + (size_t)(n0 + chunk*16 + lrow)*NPAD + k0 + lk, &Bs[chunk*512]);
    }
    __syncthreads();
    short8 af[4], bfr[4];
#pragma unroll
    for (int ti=0; ti<4; ++ti)
      af[ti] = *(const short8*)&As[(wm*64 + ti*16 + l15)*32 + quad*8];
#pragma unroll
    for (int tj=0; tj<4; ++tj)
      bfr[tj] = *(const short8*)&Bs[(wn*64 + tj*16 + l15)*32 + quad*8];
#pragma unroll
    for (int ti=0; ti<4; ++ti)
#pragma unroll
      for (int tj=0; tj<4; ++tj)
        acc[ti][tj] = __builtin_amdgcn_mfma_f32_16x16x32_bf16(af[ti], bfr[tj], acc[ti][tj], 0, 0, 0);
    __syncthreads();
  }

  const float eta  = params[1];
  const float lamc = params[2];

  // ---- coalesced epilogue: 4 chunks of [128 rows x 32 cols] via LDS ----
#pragma unroll
  for (int c=0; c<4; ++c){
    if (wn == (c>>1)){
      int tjb = (c&1)*2;
#pragma unroll
      for (int ti=0; ti<4; ++ti)
#pragma unroll
        for (int u=0; u<2; ++u)
#pragma unroll
          for (int r=0; r<4; ++r)
            fbuf[(wm*64 + ti*16 + quad*4 + r)*32 + u*16 + l15] = acc[ti][tjb+u][r];
    }
    __syncthreads();
#pragma unroll
    for (int k=0; k<4; ++k){
      int row = k*32 + (t>>3);
      int col = (t&7)*4;
      int m = m0 + row;
      int n = n0 + c*32 + col;
      size_t idx = (size_t)m*M_DIM + n;
      float4 g4 = *(const float4*)&fbuf[row*32 + col];
      float gr[4] = {g4.x, g4.y, g4.z, g4.w};
      float go4[4];
      if (MODE!=0){
        uint2 ph = *(const uint2*)(Zhi + idx);
        uint2 pl = *(const uint2*)(Zlo + idx);
        unsigned short h[4] = {(unsigned short)(ph.x&0xffff),(unsigned short)(ph.x>>16),
                               (unsigned short)(ph.y&0xffff),(unsigned short)(ph.y>>16)};
        unsigned short l[4] = {(unsigned short)(pl.x&0xffff),(unsigned short)(pl.x>>16),
                               (unsigned short)(pl.y&0xffff),(unsigned short)(pl.y>>16)};
        float4 gov = *(const float4*)(Gamma + idx);
        go4[0]=gov.x; go4[1]=gov.y; go4[2]=gov.z; go4[3]=gov.w;
#pragma unroll
        for (int e=0;e<4;e++){
          float zv = bf2f(h[e]) + bf2f(l[e]);
          gr[e] = softthr(zv - eta*gr[e], lamc);
        }
      } else {
#pragma unroll
        for (int e=0;e<4;e++) gr[e] = softthr(eta*gr[e], 0.1f);
      }
      *(float4*)(Gamma + idx) = make_float4(gr[0],gr[1],gr[2],gr[3]);
      if (MODE==1){
        float zn[4];
#pragma unroll
        for (int e=0;e<4;e++) zn[e] = gr[e] + mu*(gr[e] - go4[e]);
        unsigned short h0=f2bf(zn[0]), h1=f2bf(zn[1]), h2=f2bf(zn[2]), h3=f2bf(zn[3]);
        uint2 ph; ph.x = (unsigned)h0 | ((unsigned)h1<<16); ph.y = (unsigned)h2 | ((unsigned)h3<<16);
        uint2 pl; pl.x = pack2(zn[0]-bf2f(h0), zn[1]-bf2f(h1));
                  pl.y = pack2(zn[2]-bf2f(h2), zn[3]-bf2f(h3));
        *(uint2*)(Zhi + idx) = ph;
        *(uint2*)(Zlo + idx) = pl;
      } else if (MODE==0){
        unsigned short h0=f2bf(gr[0]), h1=f2bf(gr[1]), h2=f2bf(gr[2]), h3=f2bf(gr[3]);
        uint2 ph; ph.x = (unsigned)h0 | ((unsigned)h1<<16); ph.y = (unsigned)h2 | ((unsigned)h3<<16);
        uint2 pl; pl.x = pack2(gr[0]-bf2f(h0), gr[1]-bf2f(h1));
                  pl.y = pack2(gr[2]-bf2f(h2), gr[3]-bf2f(h3));
        *(uint2*)(Zhi + idx) = ph;
        *(uint2*)(Zlo + idx) = pl;
      } else {
        uint2 ph; ph.x = pack2(gr[0], gr[1]); ph.y = pack2(gr[2], gr[3]);
        *(uint2*)(Zhi + idx) = ph;
      }
    }
    __syncthreads();
  }
}

__global__ void norms_finalize(const float* __restrict__ nacc, const float* __restrict__ params,
                               float* __restrict__ out){
  int i = threadIdx.x;
  if (i < NITER) out[i] = sqrtf(nacc[i]) / params[3];
}

extern "C" void kernel_launch(void* const* d_in, const int* in_sizes, int n_in,
                              void* d_out, int out_size, void* d_ws, size_t ws_size,
                              hipStream_t stream){
  const float* Y  = (const float*)d_in[0];
  const float* W  = (const float*)d_in[1];
  float* out      = (float*)d_out;
  float* X        = out;
  float* Gamma    = out + XSZ;
  float* norms    = out + XSZ + GSZ;

  // ---- all scratch in ws (~104 MB; ws proven >= 134 MB) ----
  unsigned short* Zhi  = (unsigned short*)d_ws;            // [8192x2048] 33.55 MB
  unsigned short* Zlo  = Zhi  + (size_t)GSZ;               // [8192x2048] 33.55 MB
  unsigned short* Rbf  = Zlo  + (size_t)GSZ;               // [8192x800]  13.11 MB (Ybf at init)
  unsigned short* Wbf  = Rbf  + (size_t)B_DIM*NPAD;        // [896x2048]   3.67 MB
  unsigned short* WTbf = Wbf  + (size_t)NROWS_W*M_DIM;     // [2048x800]   3.28 MB
  float* Q      = (float*)(WTbf + (size_t)M_DIM*NPAD);     // [2048x2048] 16.78 MB
  float* xb0    = Q + (size_t)M_DIM*M_DIM;
  float* xb1    = xb0 + M_DIM;
  float* params = xb1 + M_DIM;
  float* accs   = params + 8;    // accs[0]=||Y||^2, accs[1..50]=per-iter ||R||^2

  setup_kernel<<<dim3(1), dim3(1024), 0, stream>>>(xb0, accs);
  sumsq_kernel<<<dim3(512), dim3(256), 0, stream>>>(Y, XSZ, accs);
  conv_w      <<<dim3(1792), dim3(256), 0, stream>>>(W, Wbf);
  transpose_w <<<dim3(64,25), dim3(256), 0, stream>>>(W, WTbf);
  conv_y      <<<dim3(B_DIM), dim3(256), 0, stream>>>(Y, Rbf);   // Rbf := Ybf for init GEMM

  compute_q<<<dim3(16,16), dim3(256), 0, stream>>>(W, Q);
  float* xa = xb0; float* xc = xb1;
  for (int it=0; it<PITER; ++it){
    pm_q<<<dim3(512), dim3(256), 0, stream>>>(xa, Q, xc);
    float* tmp = xa; xa = xc; xc = tmp;
  }
  finish_power<<<dim3(1), dim3(256), 0, stream>>>(xa, accs, params);

  // Gamma0 = soft(eta*(Y@W), 0.1); z0 = Gamma0 -> hi/lo
  mfma_nn<0><<<dim3(1024), dim3(256), 0, stream>>>(Rbf, WTbf, Gamma, Zhi, Zlo, params, 0.0f);

  float tcur = 1.0f;
  for (int it=0; it<NITER; ++it){
    mfma_nt<0><<<dim3(896), dim3(256), 0, stream>>>(Zhi, Wbf, Y, Rbf, nullptr, accs + 1 + it);
    float tsq = tcur*tcur;
    float tn  = (1.0f + sqrtf(1.0f + 4.0f*tsq)) / 2.0f;
    float mu  = (tcur - 1.0f) / tn;
    tcur = tn;
    if (it < NITER-1)
      mfma_nn<1><<<dim3(1024), dim3(256), 0, stream>>>(Rbf, WTbf, Gamma, Zhi, Zlo, params, mu);
    else
      mfma_nn<2><<<dim3(1024), dim3(256), 0, stream>>>(Rbf, WTbf, Gamma, Zhi, Zlo, params, mu);
  }

  norms_finalize<<<dim3(1), dim3(64), 0, stream>>>(accs + 1, params, norms);

  // X = Gamma @ W^T  (Zhi holds bf16 Gamma; Wbf in ws -> async B path, no aliasing)
  mfma_nt<1><<<dim3(896), dim3(256), 0, stream>>>(Zhi, Wbf, nullptr, nullptr, X, nullptr);
}